// Round 10
// baseline (320.629 us; speedup 1.0000x reference)
//
#include <hip/hip_runtime.h>

#define B_SZ 1024
#define H_SZ 2048
#define E_SZ 1024

typedef float  f32x4 __attribute__((ext_vector_type(4)));
typedef short  s16x8 __attribute__((ext_vector_type(8)));

__device__ __forceinline__ unsigned short f2bf(float f) {
    unsigned u = __float_as_uint(f);
    u = u + 0x7fffu + ((u >> 16) & 1u);   // RNE
    return (unsigned short)(u >> 16);
}
__device__ __forceinline__ float bf2f(unsigned short s) {
    return __uint_as_float(((unsigned)s) << 16);
}
__device__ __forceinline__ float sigm(float v) {
    return 1.0f / (1.0f + __expf(-v));
}
__device__ __forceinline__ unsigned cvtpk(float lo, float hi) {
    unsigned r;
    asm("v_cvt_pk_bf16_f32 %0, %1, %2" : "=v"(r) : "v"(lo), "v"(hi));
    return r;
}

__device__ __forceinline__ void gll(const unsigned short* g, unsigned short* l) {
    __builtin_amdgcn_global_load_lds(
        (const __attribute__((address_space(1))) unsigned int*)g,
        (__attribute__((address_space(3))) unsigned int*)l, 16, 0, 0);
}

// ---------------------------------------------------------------- cast pass
struct CastArgs {
    const float*    src[10];
    unsigned short* dst[10];
    int             n[10];
};

__global__ __launch_bounds__(256) void cast_kernel(CastArgs a) {
    const int arr = blockIdx.y;
    const int n = a.n[arr];
    const float* __restrict__ s = a.src[arr];
    unsigned short* __restrict__ d = a.dst[arr];
    const int stride = gridDim.x * 256 * 4;
    for (int i = (blockIdx.x * 256 + threadIdx.x) * 4; i < n; i += stride) {
        float4 v = *(const float4*)(s + i);
        ushort4 o;
        o.x = f2bf(v.x); o.y = f2bf(v.y); o.z = f2bf(v.z); o.w = f2bf(v.w);
        *(ushort4*)(d + i) = o;
    }
}

// -------------------- gates+cell: single-barrier phased pipeline ----------
// BM=256 x BN=128(4 gates x 32 H-cols). Grid 4m x 64n = 256 blocks (1/CU),
// 512 thr = 8 waves (4M x 2N), 64x64/wave. LDS: 4 half-slots (kt&1, kh):
// A 256x32 (16KB) x4 + B 128x32 (8KB) x4 = 96KB. Unified K: kt 0..15 = E,
// 16..47 = H. Phase [kt,kh] = { 8 ds_read_b128 (slot); stage 3 gll for the
// half-tile 3 phases ahead; vmcnt(6); s_barrier; lgkm(0); 16 MFMA }.
// ONE barrier/phase: barrier region spans MFMA(p)+ds_read(p+1)+stage(p+1)
// (the R1 failure was a second barrier isolating the MFMA cluster).
// vmcnt(6) leaves the newest 2 stage-batches in flight; never drains 0
// mid-loop. Tails: 6,6,3,0,0 (verified). Swizzle pos^((row>>1)&3): 2-way.
struct GatesCellArgs {
    const unsigned short *Xb, *Hb, *Wxb, *Whb;
    const float *bias[4];
    const float *cin;
    float *c_out, *h_out;
    unsigned short *HnB;
};

__global__ __launch_bounds__(512, 2) void gates_cell_kernel(GatesCellArgs a) {
    __shared__ unsigned short smem[49152];          // 96KB
    unsigned short* lA = smem;                      // 4 x 8192 elems
    unsigned short* lB = smem + 32768;              // 4 x 4096 elems

    const int t   = threadIdx.x;
    const int b   = blockIdx.x;
    const int xcd = b & 7;
    const int i_  = b >> 3;                 // 0..31 within XCD
    const int nt  = xcd * 8 + (i_ >> 2);    // 0..63 n-tile (32 H-cols)
    const int m0  = (i_ & 3) * 256;
    const int n0h = nt * 32;

    const size_t HE = (size_t)H_SZ * E_SZ, HH = (size_t)H_SZ * H_SZ;

    // staging constants: chunk c -> row=c>>2, pos=c&3; src colblk pre-swz
    const int rA  = t >> 2;                          // 0..127
    const int swz = (((t & 3) ^ ((t >> 3) & 3)) << 3);
    const unsigned short* xa  = a.Xb + (size_t)(m0 + rA) * E_SZ + swz;
    const unsigned short* xa2 = xa + (size_t)128 * E_SZ;
    const unsigned short* ha  = a.Hb + (size_t)(m0 + rA) * H_SZ + swz;
    const unsigned short* ha2 = ha + (size_t)128 * H_SZ;
    const int g    = t >> 7;                         // B gate for this thread
    const int rowB = (t >> 2) & 31;
    const unsigned short* wxSel = a.Wxb + (size_t)g * HE
                                + (size_t)(n0h + rowB) * E_SZ + swz;
    const unsigned short* whSel = a.Whb + (size_t)g * HH
                                + (size_t)(n0h + rowB) * H_SZ + swz;

    auto stage = [&](int kt, int kh, int slot) {
        unsigned short* dA = lA + slot * 8192 + t * 8;
        unsigned short* dB = lB + slot * 4096 + t * 8;
        if (kt < 16) {
            const int k = kt * 64 + kh * 32;
            gll(xa + k, dA); gll(xa2 + k, dA + 4096); gll(wxSel + k, dB);
        } else {
            const int k = (kt - 16) * 64 + kh * 32;
            gll(ha + k, dA); gll(ha2 + k, dA + 4096); gll(whSel + k, dB);
        }
    };

    // fragment offsets (swizzled), fixed per thread
    const int lane = t & 63;
    const int w    = t >> 6;
    const int wr   = (w >> 1) << 6;          // 0,64,128,192
    const int wc   = (w & 1) << 6;           // 0,64
    const int lr   = lane & 15;
    const int q4   = lane >> 4;
    int offA[4], offB[4];
#pragma unroll
    for (int i = 0; i < 4; ++i) {
        const int ra = wr + i * 16 + lr;
        offA[i] = ra * 32 + ((q4 ^ ((ra >> 1) & 3)) << 3);
        const int rb = wc + i * 16 + lr;
        offB[i] = rb * 32 + ((q4 ^ ((rb >> 1) & 3)) << 3);
    }

    f32x4 acc[4][4] = {};

    // prologue: (0,0)->s0, (0,1)->s1, (1,0)->s2 ; 9 gll, retire batch 1
    stage(0, 0, 0); stage(0, 1, 1); stage(1, 0, 2);
    asm volatile("s_waitcnt vmcnt(6)" ::: "memory");
    __builtin_amdgcn_s_barrier();

#define PHASE(SLOT, STAGE_STMT, VMC)                                      \
  {                                                                       \
    const unsigned short* pA = lA + (SLOT) * 8192;                        \
    const unsigned short* pB = lB + (SLOT) * 4096;                        \
    s16x8 af[4], bv[4];                                                   \
    af[0] = *(const s16x8*)(pA + offA[0]);                                \
    af[1] = *(const s16x8*)(pA + offA[1]);                                \
    af[2] = *(const s16x8*)(pA + offA[2]);                                \
    af[3] = *(const s16x8*)(pA + offA[3]);                                \
    bv[0] = *(const s16x8*)(pB + offB[0]);                                \
    bv[1] = *(const s16x8*)(pB + offB[1]);                                \
    bv[2] = *(const s16x8*)(pB + offB[2]);                                \
    bv[3] = *(const s16x8*)(pB + offB[3]);                                \
    STAGE_STMT;                                                           \
    asm volatile("s_waitcnt vmcnt(" VMC ")" ::: "memory");                \
    __builtin_amdgcn_s_barrier();                                         \
    asm volatile("s_waitcnt lgkmcnt(0)" ::: "memory");                    \
    __builtin_amdgcn_sched_barrier(0);                                    \
    __builtin_amdgcn_s_setprio(1);                                        \
    _Pragma("unroll") for (int i2 = 0; i2 < 4; ++i2)                      \
      _Pragma("unroll") for (int j2 = 0; j2 < 4; ++j2)                    \
        acc[i2][j2] = __builtin_amdgcn_mfma_f32_16x16x32_bf16(            \
            af[i2], bv[j2], acc[i2][j2], 0, 0, 0);                        \
    __builtin_amdgcn_s_setprio(0);                                        \
  }

    // main: kt pairs 0..45 (slots compile-time per parity)
#pragma unroll 1
    for (int mt = 0; mt < 23; ++mt) {
        const int kt = mt * 2;                      // even
        PHASE(0, stage(kt + 1, 1, 3), "6");         // [kt,0]
        PHASE(1, stage(kt + 2, 0, 0), "6");         // [kt,1]
        PHASE(2, stage(kt + 2, 1, 1), "6");         // [kt+1,0]
        PHASE(3, stage(kt + 3, 0, 2), "6");         // [kt+1,1]
    }
    // tail: kt = 46,47
    PHASE(0, stage(47, 1, 3), "6");                 // [46,0]
    PHASE(1, , "3");                                // [46,1]
    PHASE(2, , "0");                                // [47,0]
    PHASE(3, , "0");                                // [47,1]
#undef PHASE

    __syncthreads();   // all frag reads done; smem reusable

    // ---- epilogue 1: bias + activation -> exchange [256][136-stride]
    const int rq = (lane >> 4) << 2;
#pragma unroll
    for (int j = 0; j < 4; ++j) {
        const int col = wc + j * 16 + lr;       // 0..127: gate = col>>5
        const int q   = col >> 5;
        const float bvv = a.bias[q][n0h + (col & 31)];
#pragma unroll
        for (int i = 0; i < 4; ++i) {
#pragma unroll
            for (int r = 0; r < 4; ++r) {
                const int row = wr + i * 16 + rq + r;
                const float v = acc[i][j][r] + bvv;
                const float act = (q == 1) ? tanhf(v) : sigm(v);
                smem[row * 136 + col] = f2bf(act);
            }
        }
    }
    __syncthreads();

    // ---- epilogue 2: cell update, 16 h-elems/thread
    {
        const int row = t >> 1;          // 0..255
        const int hl0 = (t & 1) * 16;    // 0 or 16 within the 32 H-cols
        const unsigned short* ex = smem + row * 136;
        s16x8 i0 = *(const s16x8*)(ex + hl0);
        s16x8 i1 = *(const s16x8*)(ex + hl0 + 8);
        s16x8 g0 = *(const s16x8*)(ex + 32 + hl0);
        s16x8 g1 = *(const s16x8*)(ex + 32 + hl0 + 8);
        s16x8 f0 = *(const s16x8*)(ex + 64 + hl0);
        s16x8 f1 = *(const s16x8*)(ex + 64 + hl0 + 8);
        s16x8 o0 = *(const s16x8*)(ex + 96 + hl0);
        s16x8 o1 = *(const s16x8*)(ex + 96 + hl0 + 8);

        const size_t gidx = (size_t)(m0 + row) * H_SZ + n0h + hl0;
        float cn[16], hn[16];
#pragma unroll
        for (int k = 0; k < 16; ++k) {
            const float iv = bf2f((unsigned short)(k < 8 ? i0[k] : i1[k - 8]));
            const float gv = bf2f((unsigned short)(k < 8 ? g0[k] : g1[k - 8]));
            const float fv = bf2f((unsigned short)(k < 8 ? f0[k] : f1[k - 8]));
            const float ov = bf2f((unsigned short)(k < 8 ? o0[k] : o1[k - 8]));
            const float cv = a.cin[gidx + k];
            cn[k] = fv * cv + iv * gv;
            hn[k] = ov * cn[k];
        }
#pragma unroll
        for (int k = 0; k < 16; k += 4) {
            *(float4*)(a.c_out + gidx + k) = make_float4(cn[k], cn[k+1], cn[k+2], cn[k+3]);
            *(float4*)(a.h_out + gidx + k) = make_float4(hn[k], hn[k+1], hn[k+2], hn[k+3]);
            ushort4 hb;
            hb.x = f2bf(hn[k]);   hb.y = f2bf(hn[k+1]);
            hb.z = f2bf(hn[k+2]); hb.w = f2bf(hn[k+3]);
            *(ushort4*)(a.HnB + gidx + k) = hb;
        }
    }
}

// ---------------- y GEMM: BK=128 core, f32 Wy direct (R8-measured) -------
__device__ __forceinline__ void gemm_bk128(
    const unsigned short* __restrict__ A,
    const float* __restrict__ W,
    int ld, int kLen, int m0, int n0,
    unsigned short* lA, unsigned short* lB,
    f32x4 acc[4][4], int t)
{
    const int lane = t & 63;
    const int w    = t >> 6;
    const int wr   = (w >> 1) << 6;
    const int wc   = (w & 1) << 6;
    const int lr   = lane & 15;
    const int q4   = lane >> 4;

    const int srow = t >> 4;
    const int sblk = ((t & 15) ^ srow) << 3;
    const unsigned short* gA = A + (size_t)(m0 + srow) * ld + sblk;
    const float*          gW = W + (size_t)(n0 + srow) * ld + sblk;
    const size_t st16 = (size_t)16 * ld;

    f32x4 f0[8], f1[8];
#pragma unroll
    for (int p = 0; p < 8; ++p) {
        const float* s = gW + p * st16;
        f0[p] = *(const f32x4*)(s);
        f1[p] = *(const f32x4*)(s + 4);
    }

    for (int k0 = 0; k0 < kLen; k0 += 128) {
#pragma unroll
        for (int p = 0; p < 8; ++p) {
            uint4 pk;
            pk.x = cvtpk(f0[p].x, f0[p].y);
            pk.y = cvtpk(f0[p].z, f0[p].w);
            pk.z = cvtpk(f1[p].x, f1[p].y);
            pk.w = cvtpk(f1[p].z, f1[p].w);
            *(uint4*)(lB + (t + 256 * p) * 8) = pk;
        }
#pragma unroll
        for (int p = 0; p < 8; ++p)
            gll(gA + k0 + p * st16, lA + (t + 256 * p) * 8);
        __syncthreads();

        if (k0 + 128 < kLen) {
#pragma unroll
            for (int p = 0; p < 8; ++p) {
                const float* s = gW + (k0 + 128) + p * st16;
                f0[p] = *(const f32x4*)(s);
                f1[p] = *(const f32x4*)(s + 4);
            }
        }

#pragma unroll
        for (int ks = 0; ks < 4; ++ks) {
            s16x8 af[4], bfr[4];
#pragma unroll
            for (int i = 0; i < 4; ++i) {
                const int ra = wr + i * 16 + lr;
                af[i] = *(const s16x8*)(lA + ra * 128 +
                         ((((ks << 2) + q4) ^ (ra & 15)) << 3));
            }
#pragma unroll
            for (int j = 0; j < 4; ++j) {
                const int rb = wc + j * 16 + lr;
                bfr[j] = *(const s16x8*)(lB + rb * 128 +
                          ((((ks << 2) + q4) ^ (rb & 15)) << 3));
            }
#pragma unroll
            for (int i = 0; i < 4; ++i)
#pragma unroll
                for (int j = 0; j < 4; ++j)
                    acc[i][j] = __builtin_amdgcn_mfma_f32_16x16x32_bf16(
                        af[i], bfr[j], acc[i][j], 0, 0, 0);
        }
        __syncthreads();
    }
}

__global__ __launch_bounds__(256, 2) void y_split_kernel(
    const unsigned short* __restrict__ Hn,
    const float* __restrict__ Wy,
    float* __restrict__ part)
{
    __shared__ unsigned short lA[128 * 128];
    __shared__ unsigned short lB[128 * 128];
    const int t   = threadIdx.x;
    const int b   = blockIdx.x;
    const int xcd = b & 7;
    const int i_  = b >> 3;
    const int ns  = xcd * 4 + (i_ >> 3);
    const int m0  = (i_ & 7) * 128;
    const int n0  = (ns >> 2) * 128;
    const int s   = ns & 3;

    f32x4 acc[4][4] = {};
    gemm_bk128(Hn + s * 512, Wy + s * 512, H_SZ, 512, m0, n0, lA, lB, acc, t);

    const int lane = t & 63, w = t >> 6;
    const int wr = (w >> 1) << 6, wc = (w & 1) << 6;
    const int lr = lane & 15, rq = (lane >> 4) << 2;
    float* P = part + (size_t)s * B_SZ * E_SZ;
#pragma unroll
    for (int i = 0; i < 4; ++i) {
#pragma unroll
        for (int j = 0; j < 4; ++j) {
            const int n = n0 + wc + j * 16 + lr;
#pragma unroll
            for (int r = 0; r < 4; ++r) {
                const int m = m0 + wr + i * 16 + rq + r;
                P[(size_t)m * E_SZ + n] = acc[i][j][r];
            }
        }
    }
}

__global__ __launch_bounds__(256) void y_reduce_kernel(
    const float* __restrict__ part, const float* __restrict__ by,
    float* __restrict__ yout)
{
    const size_t BE = (size_t)B_SZ * E_SZ;
    const int idx = (blockIdx.x * 256 + threadIdx.x) * 4;
    float4 a = *(const float4*)(part + idx);
    float4 b2 = *(const float4*)(part + BE + idx);
    float4 c2 = *(const float4*)(part + 2 * BE + idx);
    float4 d2 = *(const float4*)(part + 3 * BE + idx);
    const int col = idx & (E_SZ - 1);
    float4 bv = *(const float4*)(by + col);
    float4 o;
    o.x = tanhf(a.x + b2.x + c2.x + d2.x + bv.x);
    o.y = tanhf(a.y + b2.y + c2.y + d2.y + bv.y);
    o.z = tanhf(a.z + b2.z + c2.z + d2.z + bv.z);
    o.w = tanhf(a.w + b2.w + c2.w + d2.w + bv.w);
    *(float4*)(yout + idx) = o;
}

// ---------------------------------------------------------------- launch
extern "C" void kernel_launch(void* const* d_in, const int* in_sizes, int n_in,
                              void* d_out, int out_size, void* d_ws, size_t ws_size,
                              hipStream_t stream) {
    const float* x   = (const float*)d_in[0];
    const float* c   = (const float*)d_in[1];
    const float* h   = (const float*)d_in[2];
    const float* Wxi = (const float*)d_in[3];
    const float* Whi = (const float*)d_in[4];
    const float* Bi  = (const float*)d_in[5];
    const float* Wxg = (const float*)d_in[6];
    const float* Whg = (const float*)d_in[7];
    const float* Bg  = (const float*)d_in[8];
    const float* Wxf = (const float*)d_in[9];
    const float* Whf = (const float*)d_in[10];
    const float* Bf  = (const float*)d_in[11];
    const float* Wxo = (const float*)d_in[12];
    const float* Who = (const float*)d_in[13];
    const float* Bo  = (const float*)d_in[14];
    const float* Why = (const float*)d_in[15];
    const float* By  = (const float*)d_in[16];

    const size_t BE = (size_t)B_SZ * E_SZ, BH = (size_t)B_SZ * H_SZ;
    const size_t HE = (size_t)H_SZ * E_SZ, HH = (size_t)H_SZ * H_SZ;

    unsigned short* ws  = (unsigned short*)d_ws;
    unsigned short* Xb  = ws;                 // BE bf16
    unsigned short* Hb  = Xb + BE;            // BH bf16
    unsigned short* Wxb = Hb + BH;            // 4*HE bf16 (dead after gates)
    unsigned short* Whb = Wxb + 4 * HE;       // 4*HH bf16
    unsigned short* HnB = Whb + 4 * HH;       // BH bf16
    float*          ypart = (float*)Wxb;      // 4*BE f32 aliases dead Wxb

    CastArgs ca;
    ca.src[0] = x;   ca.dst[0] = Xb;          ca.n[0] = (int)BE;
    ca.src[1] = h;   ca.dst[1] = Hb;          ca.n[1] = (int)BH;
    ca.src[2] = Wxi; ca.dst[2] = Wxb;         ca.n[2] = (int)HE;
    ca.src[3] = Wxg; ca.dst[3] = Wxb + HE;    ca.n[3] = (int)HE;
    ca.src[4] = Wxf; ca.dst[4] = Wxb + 2*HE;  ca.n[4] = (int)HE;
    ca.src[5] = Wxo; ca.dst[5] = Wxb + 3*HE;  ca.n[5] = (int)HE;
    ca.src[6] = Whi; ca.dst[6] = Whb;         ca.n[6] = (int)HH;
    ca.src[7] = Whg; ca.dst[7] = Whb + HH;    ca.n[7] = (int)HH;
    ca.src[8] = Whf; ca.dst[8] = Whb + 2*HH;  ca.n[8] = (int)HH;
    ca.src[9] = Who; ca.dst[9] = Whb + 3*HH;  ca.n[9] = (int)HH;
    hipLaunchKernelGGL(cast_kernel, dim3(512, 10), dim3(256), 0, stream, ca);

    float* y_out = (float*)d_out;
    float* c_out = y_out + BE;
    float* h_out = c_out + BH;

    GatesCellArgs ga;
    ga.Xb = Xb; ga.Hb = Hb; ga.Wxb = Wxb; ga.Whb = Whb;
    ga.bias[0] = Bi; ga.bias[1] = Bg; ga.bias[2] = Bf; ga.bias[3] = Bo;
    ga.cin = c; ga.c_out = c_out; ga.h_out = h_out; ga.HnB = HnB;
    hipLaunchKernelGGL(gates_cell_kernel, dim3(256), dim3(512), 0, stream, ga);

    hipLaunchKernelGGL(y_split_kernel, dim3(256), dim3(256), 0, stream,
                       HnB, Why, ypart);
    hipLaunchKernelGGL(y_reduce_kernel, dim3((unsigned)(BE / 1024)), dim3(256), 0, stream,
                       ypart, By, y_out);
}